// Round 7
// baseline (175.293 us; speedup 1.0000x reference)
//
#include <hip/hip_runtime.h>
#include <hip/hip_bf16.h>
#include <stdint.h>

#define SEQ    2048
#define BATCH  2
#define DMODEL 1024
#define NHEADS 16
#define HDIM   64
#define MROWS  (BATCH*SEQ)   // 4096

typedef __attribute__((ext_vector_type(8))) short bf16x8;
typedef __attribute__((ext_vector_type(4))) short bf16x4;
typedef __attribute__((ext_vector_type(4))) float f32x4;

__device__ inline void global_to_lds16(const void* g, void* l) {
  __builtin_amdgcn_global_load_lds(
      (const __attribute__((address_space(1))) uint32_t*)g,
      (__attribute__((address_space(3))) uint32_t*)l, 16, 0, 0);
}

__device__ inline unsigned short f2bf_bits(float f) {
  __hip_bfloat16 h = __float2bfloat16(f);
  return *(unsigned short*)&h;
}

// ---- prep: vectorized x->bf16 (blocks 0..1023) + vectorized W transposes ----
__global__ void prep_kernel(const float* __restrict__ x, __hip_bfloat16* __restrict__ xb,
                            const float* __restrict__ Wq, const float* __restrict__ Wk,
                            const float* __restrict__ Wv, const float* __restrict__ Wo,
                            __hip_bfloat16* __restrict__ Wqkv_t, __hip_bfloat16* __restrict__ Wo_t) {
  __shared__ float tile[64][69];
  if (blockIdx.x < 1024) {
    int base = (blockIdx.x * 256 + threadIdx.x) * 16;
    short o[16];
#pragma unroll
    for (int j = 0; j < 4; j++) {
      float4 v = *(const float4*)(x + base + j * 4);
      o[j * 4 + 0] = (short)f2bf_bits(v.x);
      o[j * 4 + 1] = (short)f2bf_bits(v.y);
      o[j * 4 + 2] = (short)f2bf_bits(v.z);
      o[j * 4 + 3] = (short)f2bf_bits(v.w);
    }
    *(bf16x8*)(xb + base) = *(const bf16x8*)&o[0];
    *(bf16x8*)(xb + base + 8) = *(const bf16x8*)&o[8];
    return;
  }
  int idx = blockIdx.x - 1024;           // 0..1023
  int z = idx >> 8;                      // 0..3 -> Wq,Wk,Wv,Wo
  int rem = idx & 255;                   // 16x16 tiles of 64x64
  const float* W = (z == 0) ? Wq : (z == 1) ? Wk : (z == 2) ? Wv : Wo;
  __hip_bfloat16* dst = (z < 3) ? (Wqkv_t + (size_t)z * 1024 * 1024) : Wo_t;
  int k0 = (rem & 15) * 64, n0 = (rem >> 4) * 64;
  int ty = threadIdx.x >> 4, tx = threadIdx.x & 15;
#pragma unroll
  for (int r = 0; r < 4; r++) {
    float4 v = *(const float4*)(W + (size_t)(k0 + ty + r * 16) * 1024 + n0 + tx * 4);
    tile[ty + r * 16][tx * 4 + 0] = v.x;
    tile[ty + r * 16][tx * 4 + 1] = v.y;
    tile[ty + r * 16][tx * 4 + 2] = v.z;
    tile[ty + r * 16][tx * 4 + 3] = v.w;
  }
  __syncthreads();
  int sy = threadIdx.x >> 3, sx = threadIdx.x & 7;
#pragma unroll
  for (int s = 0; s < 2; s++) {
    int n = sy + s * 32;
    short u[8];
#pragma unroll
    for (int i = 0; i < 8; i++) u[i] = (short)f2bf_bits(tile[sx * 8 + i][n]);
    *(bf16x8*)(dst + (size_t)(n0 + n) * 1024 + k0 + sx * 8) = *(const bf16x8*)u;
  }
}

// ========= QKV GEMM (R7): 128x128 tile, 4 waves, BK=64, 2-phase raw-barrier =========
// R6 counters for the 256x256 version: 47us, MfmaUtil 19%, Occupancy 14.6% -- 192
// blocks < 256 CUs (25% of CUs idle) and 128KiB LDS -> 1 block/CU (no cross-block
// overlap at barriers). Fix: same counted-drain schedule at 128x128 -> grid 768
// blocks (3/CU), 64KiB static LDS -> 2 resident blocks/CU (m114 overlap restored).
// XCD swizzle n-outer: each XCD's 96 consecutive tiles = 3 B-panels x 32 M -> B
// L2-hot, A streamed via L3. T2 chunk-XOR swizzle (0 conflicts measured), T5 setprio.
__global__ __launch_bounds__(256, 2)
void qkv_gemm_kernel(const __hip_bfloat16* __restrict__ A,   // xb [4096][1024]
                     const __hip_bfloat16* __restrict__ Bt,  // Wqkv_t [3072][1024]
                     __hip_bfloat16* __restrict__ QKV,       // [4096][3072] (Q,K cols only)
                     __hip_bfloat16* __restrict__ Vt) {      // [B*H*64][2048]
  __shared__ __hip_bfloat16 Asl[2][128 * 64];
  __shared__ __hip_bfloat16 Bsl[2][128 * 64];

  const int t = threadIdx.x;
  const int lane = t & 63;
  const int w = t >> 6;          // 0..3
  const int wm = w >> 1;         // 0..1
  const int wn = w & 1;          // 0..1

  // 768 blocks = 8 XCDs x 96; n-outer within XCD (3 n-cols x 32 m-tiles)
  const int wgid = blockIdx.y * 24 + blockIdx.x;
  const int swz = (wgid & 7) * 96 + (wgid >> 3);
  const int m0 = (swz & 31) * 128;
  const int n0 = (swz >> 5) * 128;

  const int fm = lane & 15;
  const int g4 = lane >> 4;
  const int csrc = (lane & 7) ^ ((lane >> 3) & 7);

  f32x4 acc[4][4];
#pragma unroll
  for (int i = 0; i < 4; i++)
#pragma unroll
    for (int j = 0; j < 4; j++) acc[i][j] = (f32x4){0.f, 0.f, 0.f, 0.f};

  auto stageA = [&](int ktt, int bufi) {
#pragma unroll
    for (int j = 0; j < 4; j++) {
      int seg = w * 4 + j;                 // 0..15
      int row = seg * 8 + (lane >> 3);     // 0..127
      global_to_lds16(A + (size_t)(m0 + row) * 1024 + ktt * 64 + csrc * 8,
                      (void*)(&Asl[bufi][0] + seg * 512 + lane * 8));
    }
  };
  auto stageB = [&](int ktt, int bufi) {
#pragma unroll
    for (int j = 0; j < 4; j++) {
      int seg = w * 4 + j;
      int row = seg * 8 + (lane >> 3);
      global_to_lds16(Bt + (size_t)(n0 + row) * 1024 + ktt * 64 + csrc * 8,
                      (void*)(&Bsl[bufi][0] + seg * 512 + lane * 8));
    }
  };

  auto load_af = [&](const __hip_bfloat16* Ab, int kk, bf16x8 (&af)[4]) {
#pragma unroll
    for (int mi = 0; mi < 4; mi++) {
      int row = wm * 64 + mi * 16 + fm;
      af[mi] = *(const bf16x8*)(Ab + row * 64 + (((kk * 4 + g4) ^ (fm & 7)) << 3));
    }
  };
  auto load_bf = [&](const __hip_bfloat16* Bb, int kk, bf16x8 (&bf)[4]) {
#pragma unroll
    for (int ni = 0; ni < 4; ni++) {
      int row = wn * 64 + ni * 16 + fm;
      bf[ni] = *(const bf16x8*)(Bb + row * 64 + (((kk * 4 + g4) ^ (fm & 7)) << 3));
    }
  };

  stageA(0, 0); stageB(0, 0);
  asm volatile("s_waitcnt vmcnt(0)" ::: "memory");
  __builtin_amdgcn_s_barrier();

  for (int kt = 0; kt < 16; ++kt) {
    const int buf = kt & 1;
    const __hip_bfloat16* Ab = &Asl[buf][0];
    const __hip_bfloat16* Bb = &Bsl[buf][0];
    bf16x8 af[4], bf[4];

    // ---- phase 1: frags kk0; stage BOTH next-tile operands (8 full-line gloads)
    load_af(Ab, 0, af);
    load_bf(Bb, 0, bf);
    if (kt < 15) { stageA(kt + 1, buf ^ 1); stageB(kt + 1, buf ^ 1); }
    __builtin_amdgcn_s_barrier();
    __builtin_amdgcn_s_setprio(1);
#pragma unroll
    for (int mi = 0; mi < 4; mi++)
#pragma unroll
      for (int ni = 0; ni < 4; ni++)
        acc[mi][ni] = __builtin_amdgcn_mfma_f32_16x16x32_bf16(af[mi], bf[ni], acc[mi][ni], 0, 0, 0);
    __builtin_amdgcn_s_setprio(0);
    __builtin_amdgcn_s_barrier();

    // ---- phase 2: frags kk1; per-tile drain (loads aged 1 phase + 2 MFMA clusters)
    load_af(Ab, 1, af);
    load_bf(Bb, 1, bf);
    __builtin_amdgcn_s_barrier();
    __builtin_amdgcn_s_setprio(1);
#pragma unroll
    for (int mi = 0; mi < 4; mi++)
#pragma unroll
      for (int ni = 0; ni < 4; ni++)
        acc[mi][ni] = __builtin_amdgcn_mfma_f32_16x16x32_bf16(af[mi], bf[ni], acc[mi][ni], 0, 0, 0);
    __builtin_amdgcn_s_setprio(0);
    asm volatile("s_waitcnt vmcnt(0)" ::: "memory");
    __builtin_amdgcn_s_barrier();
  }

  // epilogue: Q,K -> QKV bf16; V columns (n0 >= 2048) diverted transposed into Vt
  const bool vt_block = (n0 >= 2048);
#pragma unroll
  for (int mi = 0; mi < 4; mi++) {
    int mb = m0 + wm * 64 + mi * 16 + g4 * 4;
#pragma unroll
    for (int ni = 0; ni < 4; ni++) {
      int n = n0 + wn * 64 + ni * 16 + fm;
      if (vt_block) {
        int nv = n - 2048;
        int bhh = (mb >> 11) * 16 + (nv >> 6);
        int d = nv & 63;
        int ssq = mb & 2047;
        unsigned short u[4];
#pragma unroll
        for (int r = 0; r < 4; r++) u[r] = f2bf_bits(acc[mi][ni][r]);
        *(ushort4*)(Vt + ((size_t)bhh * 64 + d) * 2048 + ssq) = *(const ushort4*)u;
      } else {
#pragma unroll
        for (int r = 0; r < 4; r++)
          QKV[(size_t)(mb + r) * 3072 + n] = __float2bfloat16(acc[mi][ni][r]);
      }
    }
  }
}

// ============ output projection: 128x128 tile, 4 waves, BK=64, 2 phases/K-tile ============
__global__ __launch_bounds__(256, 2)
void oproj_kernel(const __hip_bfloat16* __restrict__ A,   // ctxb [4096][1024]
                  const __hip_bfloat16* __restrict__ Bt,  // Wo_t [1024][1024]
                  float* __restrict__ C,                  // out  [4096][1024] f32
                  const float* __restrict__ bias) {
  __shared__ __hip_bfloat16 Asl[2][128 * 64];
  __shared__ __hip_bfloat16 Bsl[2][128 * 64];

  const int t = threadIdx.x;
  const int lane = t & 63;
  const int w = t >> 6;          // 0..3
  const int wm = w >> 1;         // 0..1
  const int wn = w & 1;          // 0..1

  const int wgid = blockIdx.y * 8 + blockIdx.x;  // grid (8,32)
  const int n0 = (wgid & 7) * 128;               // n-panel = XCD id
  const int m0 = (wgid >> 3) * 128;

  const int fm = lane & 15;
  const int g4 = lane >> 4;
  const int csrc = (lane & 7) ^ ((lane >> 3) & 7);

  f32x4 acc[4][4];
#pragma unroll
  for (int i = 0; i < 4; i++)
#pragma unroll
    for (int j = 0; j < 4; j++) acc[i][j] = (f32x4){0.f, 0.f, 0.f, 0.f};

  auto stageA = [&](int ktt, int bufi) {
#pragma unroll
    for (int j = 0; j < 4; j++) {
      int seg = w * 4 + j;
      int row = seg * 8 + (lane >> 3);
      global_to_lds16(A + (size_t)(m0 + row) * 1024 + ktt * 64 + csrc * 8,
                      (void*)(&Asl[bufi][0] + seg * 512 + lane * 8));
    }
  };
  auto stageB = [&](int ktt, int bufi) {
#pragma unroll
    for (int j = 0; j < 4; j++) {
      int seg = w * 4 + j;
      int row = seg * 8 + (lane >> 3);
      global_to_lds16(Bt + (size_t)(n0 + row) * 1024 + ktt * 64 + csrc * 8,
                      (void*)(&Bsl[bufi][0] + seg * 512 + lane * 8));
    }
  };

  auto load_af = [&](const __hip_bfloat16* Ab, int kk, bf16x8 (&af)[4]) {
#pragma unroll
    for (int mi = 0; mi < 4; mi++) {
      int row = wm * 64 + mi * 16 + fm;
      af[mi] = *(const bf16x8*)(Ab + row * 64 + (((kk * 4 + g4) ^ (fm & 7)) << 3));
    }
  };
  auto load_bf = [&](const __hip_bfloat16* Bb, int kk, bf16x8 (&bf)[4]) {
#pragma unroll
    for (int ni = 0; ni < 4; ni++) {
      int row = wn * 64 + ni * 16 + fm;
      bf[ni] = *(const bf16x8*)(Bb + row * 64 + (((kk * 4 + g4) ^ (fm & 7)) << 3));
    }
  };

  stageA(0, 0); stageB(0, 0);
  asm volatile("s_waitcnt vmcnt(0)" ::: "memory");
  __builtin_amdgcn_s_barrier();

  for (int kt = 0; kt < 16; ++kt) {
    const int buf = kt & 1;
    const __hip_bfloat16* Ab = &Asl[buf][0];
    const __hip_bfloat16* Bb = &Bsl[buf][0];
    bf16x8 af[4], bf[4];

    load_af(Ab, 0, af);
    load_bf(Bb, 0, bf);
    if (kt < 15) { stageA(kt + 1, buf ^ 1); stageB(kt + 1, buf ^ 1); }
    __builtin_amdgcn_s_barrier();
    __builtin_amdgcn_s_setprio(1);
#pragma unroll
    for (int mi = 0; mi < 4; mi++)
#pragma unroll
      for (int ni = 0; ni < 4; ni++)
        acc[mi][ni] = __builtin_amdgcn_mfma_f32_16x16x32_bf16(af[mi], bf[ni], acc[mi][ni], 0, 0, 0);
    __builtin_amdgcn_s_setprio(0);
    __builtin_amdgcn_s_barrier();

    load_af(Ab, 1, af);
    load_bf(Bb, 1, bf);
    __builtin_amdgcn_s_barrier();
    __builtin_amdgcn_s_setprio(1);
#pragma unroll
    for (int mi = 0; mi < 4; mi++)
#pragma unroll
      for (int ni = 0; ni < 4; ni++)
        acc[mi][ni] = __builtin_amdgcn_mfma_f32_16x16x32_bf16(af[mi], bf[ni], acc[mi][ni], 0, 0, 0);
    __builtin_amdgcn_s_setprio(0);
    asm volatile("s_waitcnt vmcnt(0)" ::: "memory");
    __builtin_amdgcn_s_barrier();
  }

#pragma unroll
  for (int mi = 0; mi < 4; mi++) {
    int mb = m0 + wm * 64 + mi * 16 + g4 * 4;
#pragma unroll
    for (int ni = 0; ni < 4; ni++) {
      int n = n0 + wn * 64 + ni * 16 + fm;
      float bv = bias[n];
#pragma unroll
      for (int r = 0; r < 4; r++)
        C[(size_t)(mb + r) * 1024 + n] = acc[mi][ni][r] + bv;
    }
  }
}

// ---- causal flash attention: paired q-tiles, 128-kt split-fragment phases ----
__global__ __launch_bounds__(256, 2)
void attn_kernel(const __hip_bfloat16* __restrict__ QKV,
                 const __hip_bfloat16* __restrict__ Vt,
                 __hip_bfloat16* __restrict__ ctx) {
  __shared__ __hip_bfloat16 Klds[2][128 * 64];
  __shared__ __hip_bfloat16 Vlds[2][64 * 128];

  const int t = threadIdx.x;
  const int lane = t & 63;
  const int w = t >> 6;
  const int L = blockIdx.x;
  const int bh = (L & 7) + 8 * ((L >> 3) & 3);
  const int jraw = L >> 5;
  const int jb = (jraw < 8) ? jraw : 23 - jraw;
  const int qtab[2] = { jb, 31 - jb };
  const int b = bh >> 4, h = bh & 15;
  const int fm = lane & 15;
  const int g4 = lane >> 4;
  const int fk = g4 * 8;
  const size_t rowb = (size_t)b * SEQ;
  const float c = 0.18033688011112042f;

  const int krr = lane >> 3;
  const int kjc = (lane & 7) ^ krr;
  const int vrr = lane >> 4;

  bf16x8 qf[2][2];
#pragma unroll
  for (int hh = 0; hh < 2; hh++) {
    const __hip_bfloat16* qp = QKV + (rowb + qtab[hh] * 64 + w * 16 + fm) * 3072 + h * 64 + fk;
    bf16x8 r0 = *(const bf16x8*)qp;
    bf16x8 r1 = *(const bf16x8*)(qp + 32);
#pragma unroll
    for (int i = 0; i < 8; i++) {
      float f0 = __uint_as_float(((unsigned)(unsigned short)r0[i]) << 16) * c;
      float f1 = __uint_as_float(((unsigned)(unsigned short)r1[i]) << 16) * c;
      r0[i] = (short)f2bf_bits(f0);
      r1[i] = (short)f2bf_bits(f1);
    }
    qf[hh][0] = r0; qf[hh][1] = r1;
  }

  bf16x4 ones4;
#pragma unroll
  for (int i = 0; i < 4; i++) ones4[i] = (short)0x3F80;

  f32x4 acc[2][4];
  f32x4 lacc[2];
#pragma unroll
  for (int hh = 0; hh < 2; hh++) {
    lacc[hh] = (f32x4){0.f, 0.f, 0.f, 0.f};
#pragma unroll
    for (int d = 0; d < 4; d++) acc[hh][d] = (f32x4){0.f, 0.f, 0.f, 0.f};
  }

  auto stage = [&](int pt, int bufi) {
    const int kt0 = pt * 128;
#pragma unroll
    for (int i = 0; i < 4; i++) {
      int seg = i * 4 + w;
      int kr = seg * 8 + krr;
      global_to_lds16(QKV + (rowb + kt0 + kr) * 3072 + 1024 + h * 64 + kjc * 8,
                      (void*)(&Klds[bufi][0] + seg * 512 + lane * 8));
      int vd = seg * 4 + vrr;
      int vjc = (lane & 15) ^ ((seg & 1) * 4 + vrr);
      global_to_lds16(Vt + ((size_t)bh * 64 + vd) * 2048 + kt0 + vjc * 8,
                      (void*)(&Vlds[bufi][0] + seg * 512 + lane * 8));
    }
  };

  auto subcompute = [&](const bf16x8 (&kf)[2][4], const bf16x4 (&vf)[4][4], int kts) {
    const bool act0 = (kts <= qtab[0]);
    f32x4 st1[4], st0[4];
#pragma unroll
    for (int ns = 0; ns < 4; ns++) {
      st1[ns] = (f32x4){0.f, 0.f, 0.f, 0.f};
      st0[ns] = (f32x4){0.f, 0.f, 0.f, 0.f};
    }
    __builtin_amdgcn_s_setprio(1);
#pragma unroll
    for (int kk = 0; kk < 2; kk++) {
#pragma unroll
      for (int ns = 0; ns < 4; ns++)
        st1[ns] = __builtin_amdgcn_mfma_f32_16x16x32_bf16(kf[kk][ns], qf[1][kk], st1[ns], 0, 0, 0);
      if (act0)
#pragma unroll
        for (int ns = 0; ns < 4; ns++)
          st0[ns] = __builtin_amdgcn_mfma_f32_16x16x32_bf16(kf[kk][ns], qf[0][kk], st0[ns], 0, 0, 0);
    }
    __builtin_amdgcn_s_setprio(0);
    auto half = [&](const f32x4 (&st)[4], int hh) {
      const bool diag = (kts == qtab[hh]);
#pragma unroll
      for (int ns = 0; ns < 4; ns++) {
        float e[4];
#pragma unroll
        for (int r = 0; r < 4; r++) {
          float p = __builtin_amdgcn_exp2f(st[ns][r]);
          if (diag) {
            int ktl = ns * 16 + g4 * 4 + r;
            p = (ktl > w * 16 + fm) ? 0.f : p;
          }
          e[r] = p;
        }
        unsigned lo = __builtin_amdgcn_perm(__builtin_bit_cast(unsigned, e[1]),
                                            __builtin_bit_cast(unsigned, e[0]), 0x07060302u);
        unsigned hi = __builtin_amdgcn_perm(__builtin_bit_cast(unsigned, e[3]),
                                            __builtin_bit_cast(unsigned, e[2]), 0x07060302u);
        uint2 pp; pp.x = lo; pp.y = hi;
        bf16x4 pf = __builtin_bit_cast(bf16x4, pp);
        __builtin_amdgcn_s_setprio(1);
        lacc[hh] = __builtin_amdgcn_mfma_f32_16x16x16bf16_1k(pf, ones4, lacc[hh], 0, 0, 0);
#pragma unroll
        for (int dd = 0; dd < 4; dd++)
          acc[hh][dd] = __builtin_amdgcn_mfma_f32_16x16x16bf16_1k(pf, vf[dd][ns], acc[hh][dd], 0, 0, 0);
        __builtin_amdgcn_s_setprio(0);
      }
    };
    half(st1, 1);
    if (act0) half(st0, 0);
  };

  auto load_kf = [&](const __hip_bfloat16* Kb, int sc, bf16x8 (&kf)[2][4]) {
#pragma unroll
    for (int kk = 0; kk < 2; kk++)
#pragma unroll
      for (int ns = 0; ns < 4; ns++) {
        int row = sc * 64 + ns * 16 + fm;
        kf[kk][ns] = *(const bf16x8*)(Kb + row * 64 + (((kk * 4 + g4) ^ (fm & 7)) << 3));
      }
  };
  auto load_vf = [&](const __hip_bfloat16* Vb, int sc, bf16x4 (&vf)[4][4]) {
#pragma unroll
    for (int dd = 0; dd < 4; dd++)
#pragma unroll
      for (int ns = 0; ns < 4; ns++) {
        int ch = sc * 8 + ns * 2 + (g4 >> 1);
        vf[dd][ns] = *(const bf16x4*)(Vb + (dd * 16 + fm) * 128 +
                                      ((ch ^ (fm & 7)) << 3) + (g4 & 1) * 4);
      }
  };

  const int lastt = qtab[1];
  const int lastp = lastt >> 1;
  stage(0, 0);
  for (int pt = 0; pt <= lastp; ++pt) {
    __syncthreads();
    const int buf = pt & 1;
    const __hip_bfloat16* Kb = &Klds[buf][0];
    const __hip_bfloat16* Vb = &Vlds[buf][0];

    bf16x8 kf[2][4];
    bf16x4 vf[4][4];
    load_kf(Kb, 0, kf);
    load_vf(Vb, 0, vf);
    if (pt < lastp) stage(pt + 1, buf ^ 1);
    subcompute(kf, vf, pt * 2);

    if (pt * 2 + 1 <= lastt) {
      load_kf(Kb, 1, kf);
      load_vf(Vb, 1, vf);
      subcompute(kf, vf, pt * 2 + 1);
    }
  }

#pragma unroll
  for (int hh = 0; hh < 2; hh++) {
    float rl[4];
#pragma unroll
    for (int r = 0; r < 4; r++) rl[r] = __builtin_amdgcn_rcpf(lacc[hh][r]);
#pragma unroll
    for (int dd = 0; dd < 4; dd++)
#pragma unroll
      for (int r = 0; r < 4; r++) {
        int q = qtab[hh] * 64 + w * 16 + g4 * 4 + r;
        ctx[(rowb + q) * 1024 + h * 64 + dd * 16 + fm] =
            __float2bfloat16(acc[hh][dd][r] * rl[r]);
      }
  }
}

// ---------------- launch ----------------
extern "C" void kernel_launch(void* const* d_in, const int* in_sizes, int n_in,
                              void* d_out, int out_size, void* d_ws, size_t ws_size,
                              hipStream_t stream) {
  const float* x  = (const float*)d_in[0];
  const float* Wq = (const float*)d_in[1];
  const float* Wk = (const float*)d_in[2];
  const float* Wv = (const float*)d_in[3];
  const float* Wo = (const float*)d_in[4];
  const float* bo = (const float*)d_in[5];
  float* out = (float*)d_out;

  char* ws = (char*)d_ws;
  __hip_bfloat16* xb     = (__hip_bfloat16*)(ws);                      // 8 MiB
  __hip_bfloat16* Wqkv_t = (__hip_bfloat16*)(ws + (8ull  << 20));      // 6 MiB
  __hip_bfloat16* Wo_t   = (__hip_bfloat16*)(ws + (14ull << 20));      // 2 MiB
  __hip_bfloat16* QKV    = (__hip_bfloat16*)(ws + (16ull << 20));      // 24 MiB (V cols unused)
  __hip_bfloat16* ctxb   = (__hip_bfloat16*)(ws + (40ull << 20));      // 8 MiB
  __hip_bfloat16* Vt     = (__hip_bfloat16*)(ws + (48ull << 20));      // 8 MiB

  prep_kernel<<<dim3(2048), dim3(256), 0, stream>>>(x, xb, Wq, Wk, Wv, Wo, Wqkv_t, Wo_t);
  qkv_gemm_kernel<<<dim3(24, 32), dim3(256), 0, stream>>>(xb, Wqkv_t, QKV, Vt);
  attn_kernel<<<dim3(512), dim3(256), 0, stream>>>(QKV, Vt, ctxb);
  oproj_kernel<<<dim3(8, 32), dim3(256), 0, stream>>>(ctxb, Wo_t, out, bo);
}

// Round 8
// 168.093 us; speedup vs baseline: 1.0428x; 1.0428x over previous
//
#include <hip/hip_runtime.h>
#include <hip/hip_bf16.h>
#include <stdint.h>

#define SEQ    2048
#define BATCH  2
#define DMODEL 1024
#define NHEADS 16
#define HDIM   64
#define MROWS  (BATCH*SEQ)   // 4096

typedef __attribute__((ext_vector_type(8))) short bf16x8;
typedef __attribute__((ext_vector_type(4))) short bf16x4;
typedef __attribute__((ext_vector_type(4))) float f32x4;

__device__ inline void global_to_lds16(const void* g, void* l) {
  __builtin_amdgcn_global_load_lds(
      (const __attribute__((address_space(1))) uint32_t*)g,
      (__attribute__((address_space(3))) uint32_t*)l, 16, 0, 0);
}

__device__ inline unsigned short f2bf_bits(float f) {
  __hip_bfloat16 h = __float2bfloat16(f);
  return *(unsigned short*)&h;
}

// ---- prep: x->bf16 (blocks 0..4095) + W transposes (blocks 4096..8191) ----
__global__ void prep_kernel(const float* __restrict__ x, __hip_bfloat16* __restrict__ xb,
                            const float* __restrict__ Wq, const float* __restrict__ Wk,
                            const float* __restrict__ Wv, const float* __restrict__ Wo,
                            __hip_bfloat16* __restrict__ Wqkv_t, __hip_bfloat16* __restrict__ Wo_t) {
  __shared__ float tile[32][33];
  if (blockIdx.x < 4096) {
    int i = (blockIdx.x * 256 + threadIdx.x) * 4;
    float4 v = *(const float4*)(x + i);
    ushort4 o;
    o.x = f2bf_bits(v.x); o.y = f2bf_bits(v.y);
    o.z = f2bf_bits(v.z); o.w = f2bf_bits(v.w);
    *(ushort4*)(xb + i) = o;
    return;
  }
  int idx = blockIdx.x - 4096;
  int z = idx >> 10;
  int rem = idx & 1023;
  const float* W = (z == 0) ? Wq : (z == 1) ? Wk : (z == 2) ? Wv : Wo;
  __hip_bfloat16* dst = (z < 3) ? (Wqkv_t + (size_t)z * 1024 * 1024) : Wo_t;
  int k0 = (rem & 31) * 32, n0 = (rem >> 5) * 32;
  int tx = threadIdx.x & 31, ty = threadIdx.x >> 5;
#pragma unroll
  for (int r = 0; r < 4; r++)
    tile[ty + r * 8][tx] = W[(size_t)(k0 + ty + r * 8) * 1024 + n0 + tx];
  __syncthreads();
#pragma unroll
  for (int r = 0; r < 4; r++)
    dst[(size_t)(n0 + ty + r * 8) * 1024 + k0 + tx] = __float2bfloat16(tile[tx][ty + r * 8]);
}

// ------ GEMM: C[M][ldc] = A[M][1024]*Wt[N][1024]^T (+bias), BK=64, dbuf LDS ------
// Register-staged phases (R14 pattern). FUSE_VT: V projection written transposed.
template <int TN, bool OUT_BF16, int MINW, bool FUSE_VT>
__global__ __launch_bounds__(256, MINW)
void gemm_kernel(const __hip_bfloat16* __restrict__ A, const __hip_bfloat16* __restrict__ Bt,
                 void* __restrict__ C, const float* __restrict__ bias, int ldc,
                 __hip_bfloat16* __restrict__ Vt) {
  __shared__ __hip_bfloat16 Asl[2][128 * 64];
  __shared__ __hip_bfloat16 Bsl[2][TN * 64];

  const int t = threadIdx.x;
  const int lane = t & 63;
  const int w = t >> 6;
  constexpr int MI = (TN == 128) ? 4 : 2;
  const int wrow = (TN == 128) ? (w >> 1) * 64 : w * 32;
  const int wcol = (TN == 128) ? (w & 1) * 64 : 0;
  const int m0 = blockIdx.y * 128;
  const int n0 = blockIdx.x * TN;

  f32x4 acc[MI][4];
#pragma unroll
  for (int i = 0; i < MI; i++)
#pragma unroll
    for (int j = 0; j < 4; j++) acc[i][j] = (f32x4){0.f, 0.f, 0.f, 0.f};

  const int srow = lane >> 3;
  const int sjc = (lane & 7) ^ srow;
  const int fm = lane & 15;
  const int g4 = lane >> 4;

  auto stage = [&](int k0, int bufi) {
#pragma unroll
    for (int i = 0; i < 4; i++) {
      int seg = i * 4 + w;
      int r = seg * 8 + srow;
      global_to_lds16(A + (size_t)(m0 + r) * 1024 + k0 + sjc * 8,
                      (void*)(&Asl[bufi][0] + seg * 512 + lane * 8));
    }
#pragma unroll
    for (int i = 0; i < TN / 32; i++) {
      int seg = i * 4 + w;
      int r = seg * 8 + srow;
      global_to_lds16(Bt + (size_t)(n0 + r) * 1024 + k0 + sjc * 8,
                      (void*)(&Bsl[bufi][0] + seg * 512 + lane * 8));
    }
  };

  stage(0, 0);
  for (int k0 = 0; k0 < 1024; k0 += 64) {
    const int buf = (k0 >> 6) & 1;
    __syncthreads();

    bf16x8 af[2][MI], bfr[2][4];
#pragma unroll
    for (int kb = 0; kb < 2; kb++) {
#pragma unroll
      for (int mi = 0; mi < MI; mi++) {
        int row = wrow + mi * 16 + fm;
        af[kb][mi] = *(const bf16x8*)(&Asl[buf][0] + row * 64 + (((kb * 4 + g4) ^ (row & 7)) << 3));
      }
#pragma unroll
      for (int ni = 0; ni < 4; ni++) {
        int row = wcol + ni * 16 + fm;
        bfr[kb][ni] = *(const bf16x8*)(&Bsl[buf][0] + row * 64 + (((kb * 4 + g4) ^ (row & 7)) << 3));
      }
    }

    if (k0 + 64 < 1024) stage(k0 + 64, buf ^ 1);

#pragma unroll
    for (int kb = 0; kb < 2; kb++)
#pragma unroll
      for (int mi = 0; mi < MI; mi++)
#pragma unroll
        for (int ni = 0; ni < 4; ni++)
          acc[mi][ni] = __builtin_amdgcn_mfma_f32_16x16x32_bf16(af[kb][mi], bfr[kb][ni], acc[mi][ni], 0, 0, 0);
  }

  const bool vt_block = FUSE_VT && (n0 >= 2048);
#pragma unroll
  for (int mi = 0; mi < MI; mi++) {
    int mb = m0 + wrow + mi * 16 + g4 * 4;
#pragma unroll
    for (int ni = 0; ni < 4; ni++) {
      int n = n0 + wcol + ni * 16 + fm;
      if (vt_block) {
        int nv = n - 2048;
        int bhh = (mb >> 11) * 16 + (nv >> 6);
        int d = nv & 63;
        int s = mb & 2047;
        unsigned short u[4];
#pragma unroll
        for (int r = 0; r < 4; r++) u[r] = f2bf_bits(acc[mi][ni][r]);
        *(ushort4*)(Vt + ((size_t)bhh * 64 + d) * 2048 + s) = *(const ushort4*)u;
      } else {
        float bv = OUT_BF16 ? 0.f : bias[n];
#pragma unroll
        for (int r = 0; r < 4; r++) {
          if (OUT_BF16)
            ((__hip_bfloat16*)C)[(size_t)(mb + r) * ldc + n] = __float2bfloat16(acc[mi][ni][r]);
          else
            ((float*)C)[(size_t)(mb + r) * ldc + n] = acc[mi][ni][r] + bv;
        }
      }
    }
  }
}

// ---- causal flash attention: paired q-tiles, 128-kt split-fragment phases ----
// Phase (128 kt, one barrier): load sub0 frags -> prefetch(pt+1) -> compute sub0
// -> load sub1 frags (forced partial drain lands mid-phase, when the prefetch
// already has ~a sub-phase of flight) -> compute sub1. Barriers halve vs 64-kt;
// the full drain at the barrier gets a whole phase of flight. R14 rule otherwise
// respected: fragments to registers before compute; no DS op between prefetch
// and the (intentional) sub1 reload point.
__global__ __launch_bounds__(256, 2)
void attn_kernel(const __hip_bfloat16* __restrict__ QKV,
                 const __hip_bfloat16* __restrict__ Vt,
                 __hip_bfloat16* __restrict__ ctx) {
  __shared__ __hip_bfloat16 Klds[2][128 * 64];   // [buf][kt][d], chunk j at slot j^(row&7)
  __shared__ __hip_bfloat16 Vlds[2][64 * 128];   // [buf][d][kt], chunk j at slot j^(d&7)

  const int t = threadIdx.x;
  const int lane = t & 63;
  const int w = t >> 6;                    // 0..3
  const int L = blockIdx.x;                // 0..511
  const int bh = (L & 7) + 8 * ((L >> 3) & 3);   // 4 bh per XCD (wgid%8 heuristic)
  const int jraw = L >> 5;                       // 0..15
  const int jb = (jraw < 8) ? jraw : 23 - jraw;  // co-resident complementary pairs
  const int qtab[2] = { jb, 31 - jb };
  const int b = bh >> 4, h = bh & 15;
  const int fm = lane & 15;
  const int g4 = lane >> 4;
  const int fk = g4 * 8;
  const size_t rowb = (size_t)b * SEQ;
  const float c = 0.18033688011112042f;    // log2(e)/8

  const int krr = lane >> 3;               // 0..7
  const int kjc = (lane & 7) ^ krr;        // K staging swizzle
  const int vrr = lane >> 4;               // 0..3

  // Q fragments (MFMA B operands), prescaled by c
  bf16x8 qf[2][2];
#pragma unroll
  for (int hh = 0; hh < 2; hh++) {
    const __hip_bfloat16* qp = QKV + (rowb + qtab[hh] * 64 + w * 16 + fm) * 3072 + h * 64 + fk;
    bf16x8 r0 = *(const bf16x8*)qp;
    bf16x8 r1 = *(const bf16x8*)(qp + 32);
#pragma unroll
    for (int i = 0; i < 8; i++) {
      float f0 = __uint_as_float(((unsigned)(unsigned short)r0[i]) << 16) * c;
      float f1 = __uint_as_float(((unsigned)(unsigned short)r1[i]) << 16) * c;
      r0[i] = (short)f2bf_bits(f0);
      r1[i] = (short)f2bf_bits(f1);
    }
    qf[hh][0] = r0; qf[hh][1] = r1;
  }

  bf16x4 ones4;
#pragma unroll
  for (int i = 0; i < 4; i++) ones4[i] = (short)0x3F80;

  f32x4 acc[2][4];
  f32x4 lacc[2];
#pragma unroll
  for (int hh = 0; hh < 2; hh++) {
    lacc[hh] = (f32x4){0.f, 0.f, 0.f, 0.f};
#pragma unroll
    for (int d = 0; d < 4; d++) acc[hh][d] = (f32x4){0.f, 0.f, 0.f, 0.f};
  }

  // stage one 128-kt phase: K 16KB (16 segs x 8 rows) + V 16KB (16 segs x 4 d-rows)
  auto stage = [&](int pt, int bufi) {
    const int kt0 = pt * 128;
#pragma unroll
    for (int i = 0; i < 4; i++) {
      int seg = i * 4 + w;                 // 0..15
      int kr = seg * 8 + krr;              // K row 0..127
      global_to_lds16(QKV + (rowb + kt0 + kr) * 3072 + 1024 + h * 64 + kjc * 8,
                      (void*)(&Klds[bufi][0] + seg * 512 + lane * 8));
      int vd = seg * 4 + vrr;              // Vt d-row 0..63
      int vjc = (lane & 15) ^ ((seg & 1) * 4 + vrr);
      global_to_lds16(Vt + ((size_t)bh * 64 + vd) * 2048 + kt0 + vjc * 8,
                      (void*)(&Vlds[bufi][0] + seg * 512 + lane * 8));
    }
  };

  // compute one 64-kt sub-tile from pre-loaded fragments
  auto subcompute = [&](const bf16x8 (&kf)[2][4], const bf16x4 (&vf)[4][4], int kts) {
    const bool act0 = (kts <= qtab[0]);
    f32x4 st1[4], st0[4];
#pragma unroll
    for (int ns = 0; ns < 4; ns++) {
      st1[ns] = (f32x4){0.f, 0.f, 0.f, 0.f};
      st0[ns] = (f32x4){0.f, 0.f, 0.f, 0.f};
    }
#pragma unroll
    for (int kk = 0; kk < 2; kk++) {
#pragma unroll
      for (int ns = 0; ns < 4; ns++)
        st1[ns] = __builtin_amdgcn_mfma_f32_16x16x32_bf16(kf[kk][ns], qf[1][kk], st1[ns], 0, 0, 0);
      if (act0)
#pragma unroll
        for (int ns = 0; ns < 4; ns++)
          st0[ns] = __builtin_amdgcn_mfma_f32_16x16x32_bf16(kf[kk][ns], qf[0][kk], st0[ns], 0, 0, 0);
    }
    auto half = [&](const f32x4 (&st)[4], int hh) {
      const bool diag = (kts == qtab[hh]);
#pragma unroll
      for (int ns = 0; ns < 4; ns++) {
        float e[4];
#pragma unroll
        for (int r = 0; r < 4; r++) {
          float p = __builtin_amdgcn_exp2f(st[ns][r]);
          if (diag) {
            int ktl = ns * 16 + g4 * 4 + r;
            p = (ktl > w * 16 + fm) ? 0.f : p;
          }
          e[r] = p;
        }
        unsigned lo = __builtin_amdgcn_perm(__builtin_bit_cast(unsigned, e[1]),
                                            __builtin_bit_cast(unsigned, e[0]), 0x07060302u);
        unsigned hi = __builtin_amdgcn_perm(__builtin_bit_cast(unsigned, e[3]),
                                            __builtin_bit_cast(unsigned, e[2]), 0x07060302u);
        uint2 pp; pp.x = lo; pp.y = hi;
        bf16x4 pf = __builtin_bit_cast(bf16x4, pp);
        lacc[hh] = __builtin_amdgcn_mfma_f32_16x16x16bf16_1k(pf, ones4, lacc[hh], 0, 0, 0);
#pragma unroll
        for (int dd = 0; dd < 4; dd++)
          acc[hh][dd] = __builtin_amdgcn_mfma_f32_16x16x16bf16_1k(pf, vf[dd][ns], acc[hh][dd], 0, 0, 0);
      }
    };
    half(st1, 1);
    if (act0) half(st0, 0);
  };

  // fragment loaders for sub-tile sc of the current buffer
  auto load_kf = [&](const __hip_bfloat16* Kb, int sc, bf16x8 (&kf)[2][4]) {
#pragma unroll
    for (int kk = 0; kk < 2; kk++)
#pragma unroll
      for (int ns = 0; ns < 4; ns++) {
        int row = sc * 64 + ns * 16 + fm;
        kf[kk][ns] = *(const bf16x8*)(Kb + row * 64 + (((kk * 4 + g4) ^ (fm & 7)) << 3));
      }
  };
  auto load_vf = [&](const __hip_bfloat16* Vb, int sc, bf16x4 (&vf)[4][4]) {
#pragma unroll
    for (int dd = 0; dd < 4; dd++)
#pragma unroll
      for (int ns = 0; ns < 4; ns++) {
        int ch = sc * 8 + ns * 2 + (g4 >> 1);
        vf[dd][ns] = *(const bf16x4*)(Vb + (dd * 16 + fm) * 128 +
                                      ((ch ^ (fm & 7)) << 3) + (g4 & 1) * 4);
      }
  };

  const int lastt = qtab[1];               // 24..31 or 16..23
  const int lastp = lastt >> 1;
  stage(0, 0);
  for (int pt = 0; pt <= lastp; ++pt) {
    __syncthreads();                       // drains prefetch issued last phase
    const int buf = pt & 1;
    const __hip_bfloat16* Kb = &Klds[buf][0];
    const __hip_bfloat16* Vb = &Vlds[buf][0];

    // sub0: fragments -> registers, then prefetch, then compute
    bf16x8 kf[2][4];
    bf16x4 vf[4][4];
    load_kf(Kb, 0, kf);
    load_vf(Kb == Kb ? Vb : Vb, 0, vf);    // (plain call; keeps source order)
    if (pt < lastp) stage(pt + 1, buf ^ 1);
    subcompute(kf, vf, pt * 2);

    // sub1: reload fragments (partial drain lands here with ~a sub-phase of flight)
    if (pt * 2 + 1 <= lastt) {
      load_kf(Kb, 1, kf);
      load_vf(Vb, 1, vf);
      subcompute(kf, vf, pt * 2 + 1);
    }
  }

  // epilogue: ctx = acc * rcp(l)
#pragma unroll
  for (int hh = 0; hh < 2; hh++) {
    float rl[4];
#pragma unroll
    for (int r = 0; r < 4; r++) rl[r] = __builtin_amdgcn_rcpf(lacc[hh][r]);
#pragma unroll
    for (int dd = 0; dd < 4; dd++)
#pragma unroll
      for (int r = 0; r < 4; r++) {
        int q = qtab[hh] * 64 + w * 16 + g4 * 4 + r;
        ctx[(rowb + q) * 1024 + h * 64 + dd * 16 + fm] =
            __float2bfloat16(acc[hh][dd][r] * rl[r]);
      }
  }
}

// ---------------- launch ----------------
extern "C" void kernel_launch(void* const* d_in, const int* in_sizes, int n_in,
                              void* d_out, int out_size, void* d_ws, size_t ws_size,
                              hipStream_t stream) {
  const float* x  = (const float*)d_in[0];
  const float* Wq = (const float*)d_in[1];
  const float* Wk = (const float*)d_in[2];
  const float* Wv = (const float*)d_in[3];
  const float* Wo = (const float*)d_in[4];
  const float* bo = (const float*)d_in[5];
  float* out = (float*)d_out;

  char* ws = (char*)d_ws;
  __hip_bfloat16* xb     = (__hip_bfloat16*)(ws);                      // 8 MiB
  __hip_bfloat16* Wqkv_t = (__hip_bfloat16*)(ws + (8ull  << 20));      // 6 MiB
  __hip_bfloat16* Wo_t   = (__hip_bfloat16*)(ws + (14ull << 20));      // 2 MiB
  __hip_bfloat16* QKV    = (__hip_bfloat16*)(ws + (16ull << 20));      // 24 MiB (V cols unused)
  __hip_bfloat16* ctxb   = (__hip_bfloat16*)(ws + (40ull << 20));      // 8 MiB
  __hip_bfloat16* Vt     = (__hip_bfloat16*)(ws + (48ull << 20));      // 8 MiB

  prep_kernel<<<dim3(8192), dim3(256), 0, stream>>>(x, xb, Wq, Wk, Wv, Wo, Wqkv_t, Wo_t);
  gemm_kernel<128, true, 2, true><<<dim3(24, 32), dim3(256), 0, stream>>>(
      xb, Wqkv_t, (void*)QKV, nullptr, 3072, Vt);
  attn_kernel<<<dim3(512), dim3(256), 0, stream>>>(QKV, Vt, ctxb);
  gemm_kernel<64, false, 2, false><<<dim3(16, 32), dim3(256), 0, stream>>>(
      ctxb, Wo_t, (void*)out, bo, 1024, nullptr);
}